// Round 1
// baseline (1433.156 us; speedup 1.0000x reference)
//
#include <hip/hip_runtime.h>

#define N_NODES 100000
#define E_EDGES 1600000
#define F_DIM 128
#define ALPHA 0.2f

// ---------------------------------------------------------------------------
// K1: per-node scores. One wave (64 lanes) per node; lane i loads h[n, 2i:2i+2]
// as float2 (64 lanes x 8B = 512B coalesced row), computes partial dots with
// a_left and a_right, shuffle-reduces across the wave.
// ---------------------------------------------------------------------------
__global__ void score_kernel(const float* __restrict__ h,
                             const float* __restrict__ a,
                             float* __restrict__ s_left,
                             float* __restrict__ s_right) {
    const int gtid = blockIdx.x * blockDim.x + threadIdx.x;
    const int node = gtid >> 6;
    const int lane = threadIdx.x & 63;
    if (node >= N_NODES) return;

    const float2 hv = reinterpret_cast<const float2*>(h + (size_t)node * F_DIM)[lane];
    const float2 al = reinterpret_cast<const float2*>(a)[lane];          // a[0,0:128]
    const float2 ar = reinterpret_cast<const float2*>(a + F_DIM)[lane];  // a[0,128:256]

    float pl = hv.x * al.x + hv.y * al.y;
    float pr = hv.x * ar.x + hv.y * ar.y;

    #pragma unroll
    for (int off = 32; off > 0; off >>= 1) {
        pl += __shfl_down(pl, off);
        pr += __shfl_down(pr, off);
    }
    if (lane == 0) {
        s_left[node]  = pl;
        s_right[node] = pr;
    }
}

// ---------------------------------------------------------------------------
// K2: edge scatter. One wave per edge. All lanes compute the (broadcast)
// edge weight; lane 0 adds it to rowsum[src]; each lane reads h[dst] as
// float2 and atomically accumulates ee * h[dst] into out[src].
// ---------------------------------------------------------------------------
__global__ void edge_kernel(const float* __restrict__ h,
                            const int* __restrict__ src,
                            const int* __restrict__ dst,
                            const float* __restrict__ s_left,
                            const float* __restrict__ s_right,
                            float* __restrict__ out,
                            float* __restrict__ rowsum) {
    const int gtid = blockIdx.x * blockDim.x + threadIdx.x;
    const int e = gtid >> 6;
    const int lane = threadIdx.x & 63;
    if (e >= E_EDGES) return;

    const int s = src[e];
    const int d = dst[e];

    const float score = s_left[s] + s_right[d];
    const float lr = score > 0.0f ? score : ALPHA * score;
    const float ee = __expf(-lr);

    if (lane == 0) {
        atomicAdd(&rowsum[s], ee);
    }

    const float2 hv = reinterpret_cast<const float2*>(h + (size_t)d * F_DIM)[lane];
    float* o = out + (size_t)s * F_DIM + (size_t)lane * 2;
    atomicAdd(o,     ee * hv.x);
    atomicAdd(o + 1, ee * hv.y);
}

// ---------------------------------------------------------------------------
// K3: finalize. out[n,f] = relu(out[n,f] / rowsum[n]), float4 per thread.
// ---------------------------------------------------------------------------
__global__ void finalize_kernel(float* __restrict__ out,
                                const float* __restrict__ rowsum) {
    const int i = blockIdx.x * blockDim.x + threadIdx.x;
    const int total = N_NODES * (F_DIM / 4);
    if (i >= total) return;
    const int n = i / (F_DIM / 4);
    const float inv = 1.0f / rowsum[n];
    float4 v = reinterpret_cast<float4*>(out)[i];
    v.x = fmaxf(v.x * inv, 0.0f);
    v.y = fmaxf(v.y * inv, 0.0f);
    v.z = fmaxf(v.z * inv, 0.0f);
    v.w = fmaxf(v.w * inv, 0.0f);
    reinterpret_cast<float4*>(out)[i] = v;
}

extern "C" void kernel_launch(void* const* d_in, const int* in_sizes, int n_in,
                              void* d_out, int out_size, void* d_ws, size_t ws_size,
                              hipStream_t stream) {
    const float* h    = (const float*)d_in[0];   // [N, F]
    const float* a    = (const float*)d_in[1];   // [1, 2F]
    const int*   edge = (const int*)d_in[2];     // [2, E]
    const int*   src  = edge;
    const int*   dst  = edge + E_EDGES;

    float* out = (float*)d_out;                  // [N, F]

    // workspace layout: s_left [N] | s_right [N] | rowsum [N]
    float* s_left  = (float*)d_ws;
    float* s_right = s_left + N_NODES;
    float* rowsum  = s_right + N_NODES;

    // zero accumulators (graph-capture-safe async memsets)
    hipMemsetAsync(d_out, 0, (size_t)N_NODES * F_DIM * sizeof(float), stream);
    hipMemsetAsync(rowsum, 0, (size_t)N_NODES * sizeof(float), stream);

    // K1: scores — one wave per node, 4 waves per 256-thread block
    {
        const int waves_per_block = 256 / 64;
        const int blocks = (N_NODES + waves_per_block - 1) / waves_per_block;
        score_kernel<<<blocks, 256, 0, stream>>>(h, a, s_left, s_right);
    }

    // K2: edge scatter — one wave per edge
    {
        const int waves_per_block = 256 / 64;
        const int blocks = (E_EDGES + waves_per_block - 1) / waves_per_block;
        edge_kernel<<<blocks, 256, 0, stream>>>(h, src, dst, s_left, s_right, out, rowsum);
    }

    // K3: finalize
    {
        const int total = N_NODES * (F_DIM / 4);
        const int blocks = (total + 255) / 256;
        finalize_kernel<<<blocks, 256, 0, stream>>>(out, rowsum);
    }
}

// Round 2
// 336.970 us; speedup vs baseline: 4.2531x; 4.2531x over previous
//
#include <hip/hip_runtime.h>

#define N_NODES 100000
#define E_EDGES 1600000
#define F_DIM 128
#define ALPHA 0.2f

#define SCAN_BLOCK 1024
#define NUM_SCAN_BLOCKS ((N_NODES + SCAN_BLOCK - 1) / SCAN_BLOCK)  // 98

// ---------------------------------------------------------------------------
// K1: per-node scores. One wave per node; lane i holds h[n, 2i:2i+2].
// ---------------------------------------------------------------------------
__global__ void score_kernel(const float* __restrict__ h,
                             const float* __restrict__ a,
                             float* __restrict__ s_left,
                             float* __restrict__ s_right) {
    const int gtid = blockIdx.x * blockDim.x + threadIdx.x;
    const int node = gtid >> 6;
    const int lane = threadIdx.x & 63;
    if (node >= N_NODES) return;

    const float2 hv = reinterpret_cast<const float2*>(h + (size_t)node * F_DIM)[lane];
    const float2 al = reinterpret_cast<const float2*>(a)[lane];
    const float2 ar = reinterpret_cast<const float2*>(a + F_DIM)[lane];

    float pl = hv.x * al.x + hv.y * al.y;
    float pr = hv.x * ar.x + hv.y * ar.y;

    #pragma unroll
    for (int off = 32; off > 0; off >>= 1) {
        pl += __shfl_down(pl, off);
        pr += __shfl_down(pr, off);
    }
    if (lane == 0) {
        s_left[node]  = pl;
        s_right[node] = pr;
    }
}

// ---------------------------------------------------------------------------
// K2: histogram of src -> counts (int atomics on 400KB array).
// ---------------------------------------------------------------------------
__global__ void histogram_kernel(const int* __restrict__ src,
                                 int* __restrict__ counts) {
    const int e = blockIdx.x * blockDim.x + threadIdx.x;
    if (e >= E_EDGES) return;
    atomicAdd(&counts[src[e]], 1);
}

// ---------------------------------------------------------------------------
// K3a: per-block exclusive scan (1024 elems/block) + block partial sums.
// ---------------------------------------------------------------------------
__global__ void scan_block_kernel(const int* __restrict__ counts,
                                  int* __restrict__ row_start,
                                  int* __restrict__ partials) {
    __shared__ int s[SCAN_BLOCK];
    const int tid = threadIdx.x;
    const int i = blockIdx.x * SCAN_BLOCK + tid;
    const int v = (i < N_NODES) ? counts[i] : 0;
    s[tid] = v;
    __syncthreads();
    #pragma unroll
    for (int off = 1; off < SCAN_BLOCK; off <<= 1) {
        int t = (tid >= off) ? s[tid - off] : 0;
        __syncthreads();
        s[tid] += t;
        __syncthreads();
    }
    if (i < N_NODES) row_start[i] = s[tid] - v;   // exclusive within block
    if (tid == SCAN_BLOCK - 1) partials[blockIdx.x] = s[tid];  // block total
}

// ---------------------------------------------------------------------------
// K3b: exclusive scan of the block partials (NUM_SCAN_BLOCKS <= 128), 1 block.
// ---------------------------------------------------------------------------
__global__ void scan_partials_kernel(int* __restrict__ partials) {
    __shared__ int s[128];
    const int tid = threadIdx.x;
    const int v = (tid < NUM_SCAN_BLOCKS) ? partials[tid] : 0;
    s[tid] = v;
    __syncthreads();
    #pragma unroll
    for (int off = 1; off < 128; off <<= 1) {
        int t = (tid >= off) ? s[tid - off] : 0;
        __syncthreads();
        s[tid] += t;
        __syncthreads();
    }
    if (tid < NUM_SCAN_BLOCKS) partials[tid] = s[tid] - v;  // exclusive
}

// ---------------------------------------------------------------------------
// K3c: add block offsets; init cursor; write sentinel row_start[N] = E.
// ---------------------------------------------------------------------------
__global__ void add_offsets_kernel(int* __restrict__ row_start,
                                   const int* __restrict__ partials,
                                   int* __restrict__ cursor) {
    const int i = blockIdx.x * blockDim.x + threadIdx.x;
    if (i < N_NODES) {
        const int v = row_start[i] + partials[i >> 10];
        row_start[i] = v;
        cursor[i] = v;
    }
    if (i == 0) row_start[N_NODES] = E_EDGES;
}

// ---------------------------------------------------------------------------
// K4: scatter edges into CSR slots as packed {dst, bitcast(ee)}.
// ---------------------------------------------------------------------------
__global__ void scatter_kernel(const int* __restrict__ src,
                               const int* __restrict__ dst,
                               const float* __restrict__ s_left,
                               const float* __restrict__ s_right,
                               int* __restrict__ cursor,
                               int2* __restrict__ pairs) {
    const int e = blockIdx.x * blockDim.x + threadIdx.x;
    if (e >= E_EDGES) return;
    const int s = src[e];
    const int d = dst[e];
    const float score = s_left[s] + s_right[d];
    const float lr = score > 0.0f ? score : ALPHA * score;
    const float ee = __expf(-lr);
    const int pos = atomicAdd(&cursor[s], 1);
    pairs[pos] = make_int2(d, __float_as_int(ee));
}

// ---------------------------------------------------------------------------
// K5: gather. One wave per node; loop over its edge list; broadcast pair
// load + float2 h-row gather; registers accumulate; one coalesced store.
// rowsum is accumulated identically in every lane (no reduction needed).
// ---------------------------------------------------------------------------
__global__ void gather_kernel(const float* __restrict__ h,
                              const int* __restrict__ row_start,
                              const int2* __restrict__ pairs,
                              float* __restrict__ out) {
    const int gtid = blockIdx.x * blockDim.x + threadIdx.x;
    const int node = gtid >> 6;
    const int lane = threadIdx.x & 63;
    if (node >= N_NODES) return;

    const int beg = row_start[node];
    const int end = row_start[node + 1];

    float accx = 0.0f, accy = 0.0f, rs = 0.0f;
    for (int p = beg; p < end; ++p) {
        const int2 pr = pairs[p];                 // same addr in all lanes -> broadcast
        const int d = pr.x;
        const float ee = __int_as_float(pr.y);
        rs += ee;
        const float2 hv = reinterpret_cast<const float2*>(h + (size_t)d * F_DIM)[lane];
        accx += ee * hv.x;
        accy += ee * hv.y;
    }

    const float inv = 1.0f / rs;
    float2 o;
    o.x = fmaxf(accx * inv, 0.0f);
    o.y = fmaxf(accy * inv, 0.0f);
    reinterpret_cast<float2*>(out + (size_t)node * F_DIM)[lane] = o;
}

// ---------------------------------------------------------------------------
// Fallback (round-1 atomic path) if ws_size is too small for CSR buffers.
// ---------------------------------------------------------------------------
__global__ void edge_atomic_kernel(const float* __restrict__ h,
                                   const int* __restrict__ src,
                                   const int* __restrict__ dst,
                                   const float* __restrict__ s_left,
                                   const float* __restrict__ s_right,
                                   float* __restrict__ out,
                                   float* __restrict__ rowsum) {
    const int gtid = blockIdx.x * blockDim.x + threadIdx.x;
    const int e = gtid >> 6;
    const int lane = threadIdx.x & 63;
    if (e >= E_EDGES) return;
    const int s = src[e];
    const int d = dst[e];
    const float score = s_left[s] + s_right[d];
    const float lr = score > 0.0f ? score : ALPHA * score;
    const float ee = __expf(-lr);
    if (lane == 0) atomicAdd(&rowsum[s], ee);
    const float2 hv = reinterpret_cast<const float2*>(h + (size_t)d * F_DIM)[lane];
    float* o = out + (size_t)s * F_DIM + (size_t)lane * 2;
    atomicAdd(o,     ee * hv.x);
    atomicAdd(o + 1, ee * hv.y);
}

__global__ void finalize_kernel(float* __restrict__ out,
                                const float* __restrict__ rowsum) {
    const int i = blockIdx.x * blockDim.x + threadIdx.x;
    const int total = N_NODES * (F_DIM / 4);
    if (i >= total) return;
    const int n = i / (F_DIM / 4);
    const float inv = 1.0f / rowsum[n];
    float4 v = reinterpret_cast<float4*>(out)[i];
    v.x = fmaxf(v.x * inv, 0.0f);
    v.y = fmaxf(v.y * inv, 0.0f);
    v.z = fmaxf(v.z * inv, 0.0f);
    v.w = fmaxf(v.w * inv, 0.0f);
    reinterpret_cast<float4*>(out)[i] = v;
}

extern "C" void kernel_launch(void* const* d_in, const int* in_sizes, int n_in,
                              void* d_out, int out_size, void* d_ws, size_t ws_size,
                              hipStream_t stream) {
    const float* h    = (const float*)d_in[0];   // [N, F]
    const float* a    = (const float*)d_in[1];   // [1, 2F]
    const int*   edge = (const int*)d_in[2];     // [2, E]
    const int*   src  = edge;
    const int*   dst  = edge + E_EDGES;
    float* out = (float*)d_out;

    // --- workspace layout (pairs first for 8B alignment) ---
    // pairs:    E int2          = 12.8 MB
    // s_left:   N float
    // s_right:  N float
    // counts:   N int
    // row_start:N+1 int
    // cursor:   N int
    // partials: 128 int
    char* wp = (char*)d_ws;
    int2*  pairs    = (int2*)wp;                 wp += (size_t)E_EDGES * sizeof(int2);
    float* s_left   = (float*)wp;                wp += (size_t)N_NODES * sizeof(float);
    float* s_right  = (float*)wp;                wp += (size_t)N_NODES * sizeof(float);
    int*   counts   = (int*)wp;                  wp += (size_t)N_NODES * sizeof(int);
    int*   row_start= (int*)wp;                  wp += (size_t)(N_NODES + 1) * sizeof(int);
    int*   cursor   = (int*)wp;                  wp += (size_t)N_NODES * sizeof(int);
    int*   partials = (int*)wp;                  wp += 128 * sizeof(int);
    const size_t needed = (size_t)(wp - (char*)d_ws);

    const int wpb = 256 / 64;  // waves per 256-thread block

    if (ws_size < needed) {
        // -------- fallback: round-1 atomic path (needs only 1.2 MB) --------
        float* fsl = (float*)d_ws;
        float* fsr = fsl + N_NODES;
        float* frs = fsr + N_NODES;
        hipMemsetAsync(d_out, 0, (size_t)N_NODES * F_DIM * sizeof(float), stream);
        hipMemsetAsync(frs, 0, (size_t)N_NODES * sizeof(float), stream);
        score_kernel<<<(N_NODES + wpb - 1) / wpb, 256, 0, stream>>>(h, a, fsl, fsr);
        edge_atomic_kernel<<<(E_EDGES + wpb - 1) / wpb, 256, 0, stream>>>(
            h, src, dst, fsl, fsr, out, frs);
        const int total = N_NODES * (F_DIM / 4);
        finalize_kernel<<<(total + 255) / 256, 256, 0, stream>>>(out, frs);
        return;
    }

    // -------- CSR path --------
    hipMemsetAsync(counts, 0, (size_t)N_NODES * sizeof(int), stream);

    score_kernel<<<(N_NODES + wpb - 1) / wpb, 256, 0, stream>>>(h, a, s_left, s_right);

    histogram_kernel<<<(E_EDGES + 255) / 256, 256, 0, stream>>>(src, counts);

    scan_block_kernel<<<NUM_SCAN_BLOCKS, SCAN_BLOCK, 0, stream>>>(counts, row_start, partials);
    scan_partials_kernel<<<1, 128, 0, stream>>>(partials);
    add_offsets_kernel<<<(N_NODES + 255) / 256, 256, 0, stream>>>(row_start, partials, cursor);

    scatter_kernel<<<(E_EDGES + 255) / 256, 256, 0, stream>>>(
        src, dst, s_left, s_right, cursor, pairs);

    gather_kernel<<<(N_NODES + wpb - 1) / wpb, 256, 0, stream>>>(
        h, row_start, pairs, out);
}

// Round 4
// 278.957 us; speedup vs baseline: 5.1375x; 1.2080x over previous
//
#include <hip/hip_runtime.h>

#define N_NODES 100000
#define E_EDGES 1600000
#define F_DIM 128
#define ALPHA 0.2f

#define SCAN_BLOCK 1024
#define NUM_SCAN_BLOCKS ((N_NODES + SCAN_BLOCK - 1) / SCAN_BLOCK)  // 98

#define SCORE_BLOCKS (N_NODES / 4)            // 4 nodes (waves) per 256-thr block = 25000
#define HIST_BLOCKS  (E_EDGES / 256)          // 6250

// ---------------------------------------------------------------------------
// K1: fused score (blocks [0, SCORE_BLOCKS)) + src histogram (rest).
// ---------------------------------------------------------------------------
__global__ void fused_score_hist_kernel(const float* __restrict__ h,
                                        const float* __restrict__ a,
                                        float* __restrict__ s_left,
                                        float* __restrict__ s_right,
                                        const int* __restrict__ src,
                                        int* __restrict__ counts) {
    const int b = blockIdx.x;
    if (b < SCORE_BLOCKS) {
        const int node = b * 4 + (threadIdx.x >> 6);
        const int lane = threadIdx.x & 63;

        const float2 hv = reinterpret_cast<const float2*>(h + (size_t)node * F_DIM)[lane];
        const float2 al = reinterpret_cast<const float2*>(a)[lane];
        const float2 ar = reinterpret_cast<const float2*>(a + F_DIM)[lane];

        float pl = hv.x * al.x + hv.y * al.y;
        float pr = hv.x * ar.x + hv.y * ar.y;

        #pragma unroll
        for (int off = 32; off > 0; off >>= 1) {
            pl += __shfl_down(pl, off);
            pr += __shfl_down(pr, off);
        }
        if (lane == 0) {
            s_left[node]  = pl;
            s_right[node] = pr;
        }
    } else {
        const int e = (b - SCORE_BLOCKS) * 256 + threadIdx.x;
        if (e < E_EDGES) atomicAdd(&counts[src[e]], 1);
    }
}

// ---------------------------------------------------------------------------
// K2a: per-block exclusive scan (1024/block) + block totals + sentinel at
// index N_NODES (block-local; global offset added via partials on the fly).
// ---------------------------------------------------------------------------
__global__ void scan_block_kernel(const int* __restrict__ counts,
                                  int* __restrict__ row_start,
                                  int* __restrict__ partials) {
    __shared__ int s[SCAN_BLOCK];
    const int tid = threadIdx.x;
    const int i = blockIdx.x * SCAN_BLOCK + tid;
    const int v = (i < N_NODES) ? counts[i] : 0;
    s[tid] = v;
    __syncthreads();
    #pragma unroll
    for (int off = 1; off < SCAN_BLOCK; off <<= 1) {
        int t = (tid >= off) ? s[tid - off] : 0;
        __syncthreads();
        s[tid] += t;
        __syncthreads();
    }
    if (i <= N_NODES) row_start[i] = s[tid] - v;               // block-local exclusive
    if (tid == SCAN_BLOCK - 1) partials[blockIdx.x] = s[tid];  // block total
}

// ---------------------------------------------------------------------------
// K2b: exclusive scan of block partials (98 <= 128), one block.
// ---------------------------------------------------------------------------
__global__ void scan_partials_kernel(int* __restrict__ partials) {
    __shared__ int s[128];
    const int tid = threadIdx.x;
    const int v = (tid < NUM_SCAN_BLOCKS) ? partials[tid] : 0;
    s[tid] = v;
    __syncthreads();
    #pragma unroll
    for (int off = 1; off < 128; off <<= 1) {
        int t = (tid >= off) ? s[tid - off] : 0;
        __syncthreads();
        s[tid] += t;
        __syncthreads();
    }
    if (tid < NUM_SCAN_BLOCKS) partials[tid] = s[tid] - v;  // exclusive
}

// ---------------------------------------------------------------------------
// K3: scatter edges into CSR slots as packed {dst, bitcast(ee)}.
// ---------------------------------------------------------------------------
__global__ void scatter_kernel(const int* __restrict__ src,
                               const int* __restrict__ dst,
                               const float* __restrict__ s_left,
                               const float* __restrict__ s_right,
                               const int* __restrict__ row_start,
                               const int* __restrict__ partials,
                               int* __restrict__ cursor,
                               int2* __restrict__ pairs) {
    const int e = blockIdx.x * blockDim.x + threadIdx.x;
    if (e >= E_EDGES) return;
    const int s = src[e];
    const int d = dst[e];
    const float score = s_left[s] + s_right[d];
    const float lr = score > 0.0f ? score : ALPHA * score;
    const float ee = __expf(-lr);
    const int pos = row_start[s] + partials[s >> 10] + atomicAdd(&cursor[s], 1);
    pairs[pos] = make_int2(d, __float_as_int(ee));
}

// ---------------------------------------------------------------------------
// K4: gather. One wave per node; two 32-lane halves each cover the full
// 128-f row as float4. ALL loop bounds are wave-uniform (j advances the
// same in every lane); only the shfl SOURCE index jj = j + half differs
// per lane, and every shfl executes with all 64 lanes active, sources < m.
// Tail edge is processed by both halves with half 1's weight zeroed.
// ---------------------------------------------------------------------------
__global__ void gather_kernel(const float* __restrict__ h,
                              const int* __restrict__ row_start,
                              const int* __restrict__ partials,
                              const int2* __restrict__ pairs,
                              float* __restrict__ out) {
    const int gtid = blockIdx.x * blockDim.x + threadIdx.x;
    const int node = gtid >> 6;
    const int lane = threadIdx.x & 63;
    if (node >= N_NODES) return;

    const int beg = row_start[node]     + partials[node >> 10];
    const int end = row_start[node + 1] + partials[(node + 1) >> 10];

    const int half = lane >> 5;   // 0 / 1
    const int hl   = lane & 31;   // float4 column within the row
    const float4* __restrict__ h4 = reinterpret_cast<const float4*>(h);

    float4 acc = make_float4(0.0f, 0.0f, 0.0f, 0.0f);
    float rs = 0.0f;

    for (int base = beg; base < end; base += 64) {
        const int m = min(64, end - base);   // wave-uniform
        int pd = 0; float pe = 0.0f;
        if (lane < m) {
            const int2 pr = pairs[base + lane];   // coalesced per-lane preload
            pd = pr.x;
            pe = __int_as_float(pr.y);
        }

        int j = 0;  // uniform across all 64 lanes from here on
        for (; j + 8 <= m; j += 8) {
            const int jj = j + half;              // per-lane shfl index only
            const int   d0 = __shfl(pd, jj);
            const int   d1 = __shfl(pd, jj + 2);
            const int   d2 = __shfl(pd, jj + 4);
            const int   d3 = __shfl(pd, jj + 6);
            const float e0 = __shfl(pe, jj);
            const float e1 = __shfl(pe, jj + 2);
            const float e2 = __shfl(pe, jj + 4);
            const float e3 = __shfl(pe, jj + 6);
            const float4 v0 = h4[(size_t)d0 * 32 + hl];
            const float4 v1 = h4[(size_t)d1 * 32 + hl];
            const float4 v2 = h4[(size_t)d2 * 32 + hl];
            const float4 v3 = h4[(size_t)d3 * 32 + hl];
            rs += e0 + e1 + e2 + e3;
            acc.x += e0 * v0.x + e1 * v1.x + e2 * v2.x + e3 * v3.x;
            acc.y += e0 * v0.y + e1 * v1.y + e2 * v2.y + e3 * v3.y;
            acc.z += e0 * v0.z + e1 * v1.z + e2 * v2.z + e3 * v3.z;
            acc.w += e0 * v0.w + e1 * v1.w + e2 * v2.w + e3 * v3.w;
        }
        for (; j + 2 <= m; j += 2) {
            const int jj = j + half;
            const int   d  = __shfl(pd, jj);
            const float ee = __shfl(pe, jj);
            const float4 v = h4[(size_t)d * 32 + hl];
            rs += ee;
            acc.x += ee * v.x;
            acc.y += ee * v.y;
            acc.z += ee * v.z;
            acc.w += ee * v.w;
        }
        if (j < m) {                         // single leftover edge (uniform test)
            const int   d  = __shfl(pd, j);  // uniform source index
            float       ee = __shfl(pe, j);
            if (half == 1) ee = 0.0f;        // half 1 contributes nothing
            const float4 v = h4[(size_t)d * 32 + hl];
            rs += ee;
            acc.x += ee * v.x;
            acc.y += ee * v.y;
            acc.z += ee * v.z;
            acc.w += ee * v.w;
        }
    }

    // combine halves (lane i <-> lane i^32 hold the same feature columns)
    acc.x += __shfl_xor(acc.x, 32);
    acc.y += __shfl_xor(acc.y, 32);
    acc.z += __shfl_xor(acc.z, 32);
    acc.w += __shfl_xor(acc.w, 32);
    rs    += __shfl_xor(rs, 32);

    if (half == 0) {
        const float inv = 1.0f / rs;
        float4 o;
        o.x = fmaxf(acc.x * inv, 0.0f);
        o.y = fmaxf(acc.y * inv, 0.0f);
        o.z = fmaxf(acc.z * inv, 0.0f);
        o.w = fmaxf(acc.w * inv, 0.0f);
        reinterpret_cast<float4*>(out)[(size_t)node * 32 + hl] = o;
    }
}

// ---------------------------------------------------------------------------
// Fallback (atomic path) if ws_size is too small for CSR buffers.
// ---------------------------------------------------------------------------
__global__ void score_kernel(const float* __restrict__ h,
                             const float* __restrict__ a,
                             float* __restrict__ s_left,
                             float* __restrict__ s_right) {
    const int gtid = blockIdx.x * blockDim.x + threadIdx.x;
    const int node = gtid >> 6;
    const int lane = threadIdx.x & 63;
    if (node >= N_NODES) return;
    const float2 hv = reinterpret_cast<const float2*>(h + (size_t)node * F_DIM)[lane];
    const float2 al = reinterpret_cast<const float2*>(a)[lane];
    const float2 ar = reinterpret_cast<const float2*>(a + F_DIM)[lane];
    float pl = hv.x * al.x + hv.y * al.y;
    float pr = hv.x * ar.x + hv.y * ar.y;
    #pragma unroll
    for (int off = 32; off > 0; off >>= 1) {
        pl += __shfl_down(pl, off);
        pr += __shfl_down(pr, off);
    }
    if (lane == 0) { s_left[node] = pl; s_right[node] = pr; }
}

__global__ void edge_atomic_kernel(const float* __restrict__ h,
                                   const int* __restrict__ src,
                                   const int* __restrict__ dst,
                                   const float* __restrict__ s_left,
                                   const float* __restrict__ s_right,
                                   float* __restrict__ out,
                                   float* __restrict__ rowsum) {
    const int gtid = blockIdx.x * blockDim.x + threadIdx.x;
    const int e = gtid >> 6;
    const int lane = threadIdx.x & 63;
    if (e >= E_EDGES) return;
    const int s = src[e];
    const int d = dst[e];
    const float score = s_left[s] + s_right[d];
    const float lr = score > 0.0f ? score : ALPHA * score;
    const float ee = __expf(-lr);
    if (lane == 0) atomicAdd(&rowsum[s], ee);
    const float2 hv = reinterpret_cast<const float2*>(h + (size_t)d * F_DIM)[lane];
    float* o = out + (size_t)s * F_DIM + (size_t)lane * 2;
    atomicAdd(o,     ee * hv.x);
    atomicAdd(o + 1, ee * hv.y);
}

__global__ void finalize_kernel(float* __restrict__ out,
                                const float* __restrict__ rowsum) {
    const int i = blockIdx.x * blockDim.x + threadIdx.x;
    const int total = N_NODES * (F_DIM / 4);
    if (i >= total) return;
    const int n = i / (F_DIM / 4);
    const float inv = 1.0f / rowsum[n];
    float4 v = reinterpret_cast<float4*>(out)[i];
    v.x = fmaxf(v.x * inv, 0.0f);
    v.y = fmaxf(v.y * inv, 0.0f);
    v.z = fmaxf(v.z * inv, 0.0f);
    v.w = fmaxf(v.w * inv, 0.0f);
    reinterpret_cast<float4*>(out)[i] = v;
}

extern "C" void kernel_launch(void* const* d_in, const int* in_sizes, int n_in,
                              void* d_out, int out_size, void* d_ws, size_t ws_size,
                              hipStream_t stream) {
    const float* h    = (const float*)d_in[0];   // [N, F]
    const float* a    = (const float*)d_in[1];   // [1, 2F]
    const int*   edge = (const int*)d_in[2];     // [2, E]
    const int*   src  = edge;
    const int*   dst  = edge + E_EDGES;
    float* out = (float*)d_out;

    // --- workspace layout (pairs first for 8B alignment) ---
    char* wp = (char*)d_ws;
    int2*  pairs    = (int2*)wp;      wp += (size_t)E_EDGES * sizeof(int2);
    float* s_left   = (float*)wp;     wp += (size_t)N_NODES * sizeof(float);
    float* s_right  = (float*)wp;     wp += (size_t)N_NODES * sizeof(float);
    int*   counts   = (int*)wp;       wp += (size_t)N_NODES * sizeof(int);
    int*   cursor   = (int*)wp;       wp += (size_t)N_NODES * sizeof(int);
    int*   row_start= (int*)wp;       wp += (size_t)(N_NODES + 1) * sizeof(int);
    int*   partials = (int*)wp;       wp += 128 * sizeof(int);
    const size_t needed = (size_t)(wp - (char*)d_ws);

    const int wpb = 256 / 64;

    if (ws_size < needed) {
        // -------- fallback: atomic path (needs only 1.2 MB) --------
        float* fsl = (float*)d_ws;
        float* fsr = fsl + N_NODES;
        float* frs = fsr + N_NODES;
        hipMemsetAsync(d_out, 0, (size_t)N_NODES * F_DIM * sizeof(float), stream);
        hipMemsetAsync(frs, 0, (size_t)N_NODES * sizeof(float), stream);
        score_kernel<<<(N_NODES + wpb - 1) / wpb, 256, 0, stream>>>(h, a, fsl, fsr);
        edge_atomic_kernel<<<(E_EDGES + wpb - 1) / wpb, 256, 0, stream>>>(
            h, src, dst, fsl, fsr, out, frs);
        const int total = N_NODES * (F_DIM / 4);
        finalize_kernel<<<(total + 255) / 256, 256, 0, stream>>>(out, frs);
        return;
    }

    // -------- CSR path --------
    hipMemsetAsync(counts, 0, (size_t)2 * N_NODES * sizeof(int), stream);  // counts+cursor

    fused_score_hist_kernel<<<SCORE_BLOCKS + HIST_BLOCKS, 256, 0, stream>>>(
        h, a, s_left, s_right, src, counts);

    scan_block_kernel<<<NUM_SCAN_BLOCKS, SCAN_BLOCK, 0, stream>>>(counts, row_start, partials);
    scan_partials_kernel<<<1, 128, 0, stream>>>(partials);

    scatter_kernel<<<(E_EDGES + 255) / 256, 256, 0, stream>>>(
        src, dst, s_left, s_right, row_start, partials, cursor, pairs);

    gather_kernel<<<(N_NODES + wpb - 1) / wpb, 256, 0, stream>>>(
        h, row_start, partials, pairs, out);
}